// Round 11
// baseline (4661.228 us; speedup 1.0000x reference)
//
#include <hip/hip_runtime.h>
#include <math.h>

// VanillaRNN, bit-exact (R4-R10 PASS) + R11: halve LDS broadcast reads.
//
// Numerics (FROZEN — chaotic recurrence, bitwise match):
//   * per row i: z = single ascending-k FMA chain k=0..255, init 0, split in
//     program order across 4 stage-groups (k-quarters) with exact-float LDS
//     handoffs (bit-safe: R7-R10) -> identical op sequence.
//   * z = ((W_hx*x_t) + chain) + bias_h, separately rounded, left-assoc
//   * tanh = Eigen/XLA fast-tanh WITH FMA (clamp 7.99881172180175781f)
//
// R11 theory: R8/R9/R10 all neutral => not VALU-tax, not addressing, not
// budget. Arithmetic that fits all data: ~528 broadcast ds_read_b128 per
// step per CU x ~6 cyc LDS-pipe = ~3200 cyc ~= the 3634-cyc step; VALU
// (2290) hides under it. Total read count is invariant to k-splitting but
// NOT to rows/thread: 2 rows/thread share one h-stream -> 8 fma per b128
// read -> reads/step 512 -> 256.
// Structure: WG=512 = 4 k-groups x 128 threads; thread (g, r=tid&127) owns
// rows r and r+128, k in [64g, 64g+64); w = wa[64]+wb[64] regs. 4-stage
// pipeline over 2 columns: phases (G0,G2),(G1,G3),(G2,G0),(G3,G1); 4
// barriers/step; zpart chain handoffs zb0/zb1/zb2 per col.

#define TT 2048
#define BB 512
#define HH 256
#define CC 10
#define KH 64    // k-quarter per stage

__device__ __forceinline__ float ref_tanhf(float x)
{
    const float a1  = 4.89352455891786e-03f;
    const float a3  = 6.37261928875436e-04f;
    const float a5  = 1.48572235717979e-05f;
    const float a7  = 5.12229709037114e-08f;
    const float a9  = -8.60467152213735e-11f;
    const float a11 = 2.00018790482477e-13f;
    const float a13 = -2.76076847742355e-16f;
    const float b0  = 4.89352518554385e-03f;
    const float b2  = 2.26843463243900e-03f;
    const float b4  = 1.18534705686654e-04f;
    const float b6  = 1.19825839466702e-06f;

    const float kClamp = 7.99881172180175781f;
    const float xc = fmaxf(fminf(x, kClamp), -kClamp);
    const float x2 = __fmul_rn(xc, xc);
    float p = fmaf(x2, a13, a11);
    p = fmaf(x2, p, a9);
    p = fmaf(x2, p, a7);
    p = fmaf(x2, p, a5);
    p = fmaf(x2, p, a3);
    p = fmaf(x2, p, a1);
    p = __fmul_rn(xc, p);
    float q = fmaf(x2, b6, b4);
    q = fmaf(x2, q, b2);
    q = fmaf(x2, q, b0);
    const float r = __fdiv_rn(p, q);
    return (fabsf(x) < 0.0004f) ? x : r;
}

__global__ __launch_bounds__(512, 2)
void rnn_fwd(const float* __restrict__ x,
             const float* __restrict__ W_hx,
             const float* __restrict__ W_hh,
             const float* __restrict__ W_ph,
             const float* __restrict__ bias_h,
             const float* __restrict__ bias_p,
             float* __restrict__ out)
{
    const int tid   = threadIdx.x;
    const int group = tid >> 7;          // stage / k-quarter 0..3
    const int r     = tid & 127;         // rows r and r+128
    const int b0    = blockIdx.x * 2;    // two batch columns per WG

    __shared__ __align__(16) float xls[2][TT];        // 16 KB
    __shared__ __align__(16) float hbuf[2][2][HH];    // [col][parity][row] 4 KB
    __shared__ __align__(16) float zb0[2][HH];        // stage0->1 handoff
    __shared__ __align__(16) float zb1[2][HH];        // stage1->2
    __shared__ __align__(16) float zb2[2][HH];        // stage2->3

    // --- stage W_hh: rows r and r+128, k-quarter [64g, 64g+64) -> regs ---
    float wa[KH], wb[KH];
    {
        const float* __restrict__ wra = W_hh + (size_t)r * HH + group * KH;
        const float* __restrict__ wrb = W_hh + (size_t)(r + 128) * HH + group * KH;
#pragma unroll
        for (int k = 0; k < KH; k += 4) {
            const float4 va = *reinterpret_cast<const float4*>(wra + k);
            wa[k] = va.x; wa[k + 1] = va.y; wa[k + 2] = va.z; wa[k + 3] = va.w;
            const float4 vb = *reinterpret_cast<const float4*>(wrb + k);
            wb[k] = vb.x; wb[k + 1] = vb.y; wb[k + 2] = vb.z; wb[k + 3] = vb.w;
        }
    }
#pragma unroll
    for (int k = 0; k < KH; ++k) {
        asm volatile("" : "+v"(wa[k]));
        asm volatile("" : "+v"(wb[k]));
    }

    // --- stage x rows (2*TT contiguous floats) -> LDS ---
    {
        const float4* __restrict__ xsrc =
            reinterpret_cast<const float4*>(x + (size_t)b0 * TT);
        float4* __restrict__ xdst = reinterpret_cast<float4*>(&xls[0][0]);
        xdst[tid]       = xsrc[tid];
        xdst[512 + tid] = xsrc[512 + tid];
    }
    const float whxa = W_hx[r];
    const float whxb = W_hx[r + 128];
    const float bha  = bias_h[r];
    const float bhb  = bias_h[r + 128];

    // h(-1) = 0 at parity 1 (step t reads wp(t-1)=(t-1)&1, writes t&1)
    if (tid < 256)      hbuf[0][1][tid] = 0.0f;
    else                hbuf[1][1][tid - 256] = 0.0f;
    __syncthreads();

// Stage bodies. K-base per stage is a literal (stage == group, 1:1).
// SnB(COL, RP): reads h[COL][RP][kbase..kbase+63] broadcast, 8 fma per b128.
#define CHAIN4(ZA, ZB, W_A, W_B, H4, K)                                       \
    ZA = fmaf(W_A[(K)],     H4.x, ZA);  ZB = fmaf(W_B[(K)],     H4.x, ZB);    \
    ZA = fmaf(W_A[(K) + 1], H4.y, ZA);  ZB = fmaf(W_B[(K) + 1], H4.y, ZB);    \
    ZA = fmaf(W_A[(K) + 2], H4.z, ZA);  ZB = fmaf(W_B[(K) + 2], H4.z, ZB);    \
    ZA = fmaf(W_A[(K) + 3], H4.w, ZA);  ZB = fmaf(W_B[(K) + 3], H4.w, ZB);

#define S0B(COL, RP)                                                          \
    {                                                                         \
        const float* __restrict__ h = &hbuf[(COL)][(RP)][0];                  \
        float za = 0.0f, zv = 0.0f;                                           \
        _Pragma("unroll")                                                     \
        for (int j = 0; j < KH; j += 4) {                                     \
            const float4 h4 = *reinterpret_cast<const float4*>(h + j);        \
            CHAIN4(za, zv, wa, wb, h4, j)                                     \
        }                                                                     \
        zb0[(COL)][r] = za;  zb0[(COL)][r + 128] = zv;                        \
    }

#define S1B(COL, RP)                                                          \
    {                                                                         \
        const float* __restrict__ h = &hbuf[(COL)][(RP)][KH];                 \
        float za = zb0[(COL)][r], zv = zb0[(COL)][r + 128];                   \
        _Pragma("unroll")                                                     \
        for (int j = 0; j < KH; j += 4) {                                     \
            const float4 h4 = *reinterpret_cast<const float4*>(h + j);        \
            CHAIN4(za, zv, wa, wb, h4, j)                                     \
        }                                                                     \
        zb1[(COL)][r] = za;  zb1[(COL)][r + 128] = zv;                        \
    }

#define S2B(COL, RP)                                                          \
    {                                                                         \
        const float* __restrict__ h = &hbuf[(COL)][(RP)][2 * KH];             \
        float za = zb1[(COL)][r], zv = zb1[(COL)][r + 128];                   \
        _Pragma("unroll")                                                     \
        for (int j = 0; j < KH; j += 4) {                                     \
            const float4 h4 = *reinterpret_cast<const float4*>(h + j);        \
            CHAIN4(za, zv, wa, wb, h4, j)                                     \
        }                                                                     \
        zb2[(COL)][r] = za;  zb2[(COL)][r + 128] = zv;                        \
    }

// S3B reads parity RPX, finishes chain, writes h at parity RPX^1.
#define S3B(COL, RPX, T)                                                      \
    {                                                                         \
        const float* __restrict__ h = &hbuf[(COL)][(RPX)][3 * KH];            \
        float za = zb2[(COL)][r], zv = zb2[(COL)][r + 128];                   \
        _Pragma("unroll")                                                     \
        for (int j = 0; j < KH; j += 4) {                                     \
            const float4 h4 = *reinterpret_cast<const float4*>(h + j);        \
            CHAIN4(za, zv, wa, wb, h4, j)                                     \
        }                                                                     \
        const float xt = xls[(COL)][(T)];                                     \
        const float aa = __fmul_rn(whxa, xt);                                 \
        const float ab = __fmul_rn(whxb, xt);                                 \
        za = __fadd_rn(__fadd_rn(aa, za), bha);                               \
        zv = __fadd_rn(__fadd_rn(ab, zv), bhb);                               \
        hbuf[(COL)][(RPX) ^ 1][r]       = ref_tanhf(za);                      \
        hbuf[(COL)][(RPX) ^ 1][r + 128] = ref_tanhf(zv);                      \
    }

// One step t: 4 phases. WP = t&1 (literal), RP = WP^1.
// ph0: G0 S0(0,t) rd RP   | G2 S2(1,t-1) rd WP
// ph1: G1 S1(0,t) rd RP   | G3 S3(1,t-1) rd WP, wr RP
// ph2: G2 S2(0,t) rd RP   | G0 S0(1,t)   rd RP
// ph3: G3 S3(0,t) rd RP wr WP | G1 S1(1,t) rd RP
#define STEP(T, WP, RP, HD)                                                   \
    {                                                                         \
        if (group == 0) { S0B(0, RP) }                                        \
        else if (!(HD) && group == 2) { S2B(1, WP) }                          \
        __syncthreads();                                                      \
        if (group == 1) { S1B(0, RP) }                                        \
        else if (!(HD) && group == 3) { S3B(1, WP, (T) - 1) }                 \
        __syncthreads();                                                      \
        if (group == 2) { S2B(0, RP) }                                        \
        else if (group == 0) { S0B(1, RP) }                                   \
        __syncthreads();                                                      \
        if (group == 3) { S3B(0, RP, T) }                                     \
        else if (group == 1) { S1B(1, RP) }                                   \
        __syncthreads();                                                      \
    }

    STEP(0, 0, 1, 1)          // head: item (1,-1) slots skipped
    STEP(1, 1, 0, 0)
    for (int t = 2; t < TT; t += 2) {
        STEP(t, 0, 1, 0)
        STEP(t + 1, 1, 0, 0)
    }
    // tail: finish (1, TT-1): stages 2,3 (reads parity wp(TT-2)=0, writes 1)
    if (group == 2) { S2B(1, 0) }
    __syncthreads();
    if (group == 3) { S3B(1, 0, TT - 1) }
    __syncthreads();

#undef STEP
#undef S3B
#undef S2B
#undef S1B
#undef S0B
#undef CHAIN4

    // epilogue: p[b,c] = sum_k h_T[k]*W_ph[c,k] + bias_p[c]
    // last writes land at parity 1 for both columns.
    if (tid < 2 * CC) {
        const int col = tid / CC;
        const int c   = tid % CC;
        const float* __restrict__ wp = W_ph + (size_t)c * HH;
        const float* __restrict__ hf = hbuf[col][1];
        float pv = 0.0f;
#pragma unroll 8
        for (int k = 0; k < HH; ++k) {
            pv = fmaf(hf[k], wp[k], pv);
        }
        out[(size_t)(b0 + col) * CC + c] = __fadd_rn(pv, bias_p[c]);
    }
}

extern "C" void kernel_launch(void* const* d_in, const int* in_sizes, int n_in,
                              void* d_out, int out_size, void* d_ws, size_t ws_size,
                              hipStream_t stream) {
    const float* x      = (const float*)d_in[0];
    const float* W_hx   = (const float*)d_in[1];
    const float* W_hh   = (const float*)d_in[2];
    const float* W_ph   = (const float*)d_in[3];
    const float* bias_h = (const float*)d_in[4];
    const float* bias_p = (const float*)d_in[5];
    float* out = (float*)d_out;

    rnn_fwd<<<dim3(BB / 2), dim3(512), 0, stream>>>(x, W_hx, W_hh, W_ph, bias_h, bias_p, out);
}